// Round 12
// baseline (359.874 us; speedup 1.0000x reference)
//
#include <hip/hip_runtime.h>
#include <stdint.h>

#define N_ROWS 4096
#define D_DIM  1024
#define ROWB   1024   // bytes per row in fp8
#define T_TEMP 0.15f

#define AS1 __attribute__((address_space(1)))
#define AS3 __attribute__((address_space(3)))

typedef float f32x4  __attribute__((ext_vector_type(4)));
typedef int   i32x4v __attribute__((ext_vector_type(4)));
typedef int   i32x8  __attribute__((ext_vector_type(8)));

__device__ __forceinline__ float wsum(float v) {
#pragma unroll
  for (int m = 32; m >= 1; m >>= 1) v += __shfl_xor(v, m, 64);
  return v;
}
__device__ __forceinline__ float wmax(float v) {
#pragma unroll
  for (int m = 32; m >= 1; m >>= 1) v = fmaxf(v, __shfl_xor(v, m, 64));
  return v;
}

// One WAVE per row (no barriers): norms, x.y dot (-> log pos), softmax-JS
// per-row term -> js[row]. fp8-e4m3 casts stored INTERLEAVED into
// Bb = [x;y] (format verified end-to-end R10/R11, absmax 0). Zeroes rowsum.
__global__ __launch_bounds__(256) void prep_kernel(
    const float* __restrict__ x, const float* __restrict__ y,
    unsigned char* __restrict__ Bb, float* __restrict__ inv_n,
    float* __restrict__ logpos, float* __restrict__ js,
    float* __restrict__ rowsum) {
  if (threadIdx.x < 4) rowsum[blockIdx.x * 4 + threadIdx.x] = 0.0f;

  const int wid = threadIdx.x >> 6, lane = threadIdx.x & 63;
  const int row = blockIdx.x * 4 + wid;
  const float4* xp = (const float4*)(x + (size_t)row * D_DIM) + lane * 4;
  const float4* yp = (const float4*)(y + (size_t)row * D_DIM) + lane * 4;

  float xv[16], yv[16];
#pragma unroll
  for (int i = 0; i < 4; ++i) {
    float4 a = xp[i], b = yp[i];
    xv[i*4+0]=a.x; xv[i*4+1]=a.y; xv[i*4+2]=a.z; xv[i*4+3]=a.w;
    yv[i*4+0]=b.x; yv[i*4+1]=b.y; yv[i*4+2]=b.z; yv[i*4+3]=b.w;
  }

  float sx2=0.f, sy2=0.f, sxy=0.f, mx=-1e30f, my=-1e30f;
#pragma unroll
  for (int k = 0; k < 16; ++k) {
    sx2 = fmaf(xv[k], xv[k], sx2);
    sy2 = fmaf(yv[k], yv[k], sy2);
    sxy = fmaf(xv[k], yv[k], sxy);
    mx = fmaxf(mx, xv[k]); my = fmaxf(my, yv[k]);
  }
  sx2 = wsum(sx2); sy2 = wsum(sy2); sxy = wsum(sxy);
  mx = wmax(mx);  my = wmax(my);

  float ex[16], ey[16], sex=0.f, sey=0.f;
#pragma unroll
  for (int k = 0; k < 16; ++k) {
    ex[k] = __expf(xv[k] - mx); ey[k] = __expf(yv[k] - my);
    sex += ex[k]; sey += ey[k];
  }
  sex = wsum(sex); sey = wsum(sey);
  const float lsex = __logf(sex), lsey = __logf(sey);
  const float rsex = 1.f / sex,  rsey = 1.f / sey;

  float term = 0.f;
#pragma unroll
  for (int k = 0; k < 16; ++k) {
    float a = ex[k] * rsex, b = ey[k] * rsey;
    float lm = __logf(0.5f * (a + b));
    term += a * ((xv[k] - mx - lsex) - lm) + b * ((yv[k] - my - lsey) - lm);
  }
  term = wsum(term);

  if (lane == 0) {
    const float nx = sqrtf(sx2), ny = sqrtf(sy2);
    inv_n[row] = 1.f / nx;
    inv_n[N_ROWS + row] = 1.f / ny;
    logpos[row] = sxy / fmaxf(nx * ny, 1e-8f) / T_TEMP;  // ln(pos)
    js[row] = term;
  }

  int p[4], q[4];
#pragma unroll
  for (int w = 0; w < 4; ++w) {
    int v = 0;
    v = __builtin_amdgcn_cvt_pk_fp8_f32(xv[w*4+0], xv[w*4+1], v, false);
    v = __builtin_amdgcn_cvt_pk_fp8_f32(xv[w*4+2], xv[w*4+3], v, true);
    p[w] = v;
    int u = 0;
    u = __builtin_amdgcn_cvt_pk_fp8_f32(yv[w*4+0], yv[w*4+1], u, false);
    u = __builtin_amdgcn_cvt_pk_fp8_f32(yv[w*4+2], yv[w*4+3], u, true);
    q[w] = u;
  }
  // interleaved store: lane's 16 bytes = chunks (2l, 2l+1) of group l>>2,
  // kk = (l&3)>>1, h0 = (l&3 & 1)*2; dest = group*64 + h*16 + kk*8.
  const int ktp = lane >> 2;
  const int lq  = lane & 3;
  const int kkb = lq >> 1;
  const int h0  = (lq & 1) * 2;
  {
    char* ob = (char*)Bb + (size_t)row * ROWB + ktp * 64 + kkb * 8 + h0 * 16;
    *(int2*)(ob)      = make_int2(p[0], p[1]);
    *(int2*)(ob + 16) = make_int2(p[2], p[3]);
    char* oy = (char*)Bb + (size_t)(N_ROWS + row) * ROWB + ktp * 64 + kkb * 8 + h0 * 16;
    *(int2*)(oy)      = make_int2(q[0], q[1]);
    *(int2*)(oy + 16) = make_int2(q[2], q[3]);
  }
}

// ===== MX-fp8 K=128 symmetric fused GEMM, 128x128, 4 waves =====
// LDS image identical to R11 (two [128][64] planes per matrix, slot-XOR
// (r>>1)&3, measured ZERO conflicts). Compute: one
// mfma_scale_f32_16x16x128_f8f6f4 (unit scales) per (m,n) per K-tile --
// lane (lo,hi)'s 8-reg operand = two b128 from plane hi>>1 at slots
// (c0^xr),((c0+1)^xr), c0=(2hi)&3 (all 8-lane phases hit 8 distinct
// bank-quads). Valid because MFMA is invariant under a common A/B
// k-permutation (prep's interleave is the same sigma for both).
// JIT-B keeps VGPR under the 168 cap (3 waves/SIMD, 3 blocks/CU).
#define GLL(src, dst) __builtin_amdgcn_global_load_lds((const AS1 void*)(src), (AS3 void*)(dst), 16, 0, 0)

__global__ __launch_bounds__(256, 3) void gemm_fused(
    const unsigned char* __restrict__ Bb, const float* __restrict__ inv_n,
    float* __restrict__ rowsum) {
  __shared__ __align__(16) char As[2 * 8192];   // [plane][128][64]
  __shared__ __align__(16) char Bs[2 * 8192];
  const int tid = threadIdx.x;
  const int wid = tid >> 6, lane = tid & 63;
  const int lo = lane & 15, hi = lane >> 4;

  int bi, bj;
  bool sym = false;
  {
    const int idx = blockIdx.x;
    if (idx < 1024) {
      bi = idx >> 5; bj = 32 + (idx & 31);
    } else {
      const int t = idx - 1024;
      int b = (int)((65.0 - sqrt((double)(4225 - 8 * t))) * 0.5);
      while ((b + 1) * (65 - (b + 1)) / 2 <= t) ++b;
      while (b * (65 - b) / 2 > t) --b;
      bi = b;
      bj = b + (t - b * (65 - b) / 2);
      sym = (bi != bj);
    }
  }
  const int grow0 = bi * 128;
  const int gcol0 = bj * 128;
  const int wrow = (wid >> 1) * 64, wcol = (wid & 1) * 64;

  f32x4 acc[4][4] = {};

  // staging (R11-identical): GLL call q: plane q>>1, rows (q&1)*64+(t>>2),
  // slot t&3; source 16B pre-swizzled h = (t&3) ^ ((t>>3)&3).
  const int sr = tid >> 2;
  const int sh = (tid & 3) ^ ((tid >> 3) & 3);
  const char* gA = (const char*)Bb + (size_t)(grow0 + sr) * ROWB + sh * 16;
  const char* gB = (const char*)Bb + (size_t)(gcol0 + sr) * ROWB + sh * 16;
  char* dA = As + tid * 16;
  char* dB = Bs + tid * 16;

  // fragment read: plane = hi>>1, row = base + lo, slots (c0^xr), (c0+1)^xr
  const int xr = (lo >> 1) & 3;
  const int c0 = (2 * hi) & 3;
  const int s0 = (c0 ^ xr) * 16;
  const int s1 = ((c0 + 1) ^ xr) * 16;
  const int po = (hi >> 1) * 8192;

  union U8 { i32x8 w; i32x4v h[2]; };

  for (int kt = 0; kt < 8; ++kt) {
    __syncthreads();   // prior reads done before overwrite
#pragma unroll
    for (int q = 0; q < 4; ++q) {
      const size_t goff = (size_t)((q & 1) * 64) * ROWB + (q >> 1) * 64 + kt * 128;
      GLL(gA + goff, dA + q * 4096);
      GLL(gB + goff, dB + q * 4096);
    }
    __syncthreads();   // staging visible

    U8 a[4];
#pragma unroll
    for (int m = 0; m < 4; ++m) {
      const char* base = As + po + (wrow + m * 16 + lo) * 64;
      a[m].h[0] = *(const i32x4v*)(base + s0);
      a[m].h[1] = *(const i32x4v*)(base + s1);
    }
#pragma unroll
    for (int n = 0; n < 4; ++n) {
      U8 bv;
      const char* base = Bs + po + (wcol + n * 16 + lo) * 64;
      bv.h[0] = *(const i32x4v*)(base + s0);
      bv.h[1] = *(const i32x4v*)(base + s1);
#pragma unroll
      for (int m = 0; m < 4; ++m)
        acc[m][n] = __builtin_amdgcn_mfma_scale_f32_16x16x128_f8f6f4(
            a[m].w, bv.w, acc[m][n], 0, 0,           // cbsz=fp8, blgp=fp8
            0, 0x7F7F7F7F, 0, 0x7F7F7F7F);           // unit E8M0 scales
    }
  }

  // epilogue: scale -> exp2 -> mask diag -> row-reduce (+col-reduce if sym)
  const float C = 1.4426950408889634f / T_TEMP;   // log2(e)/T
  float invc[4], invr[4][4];
#pragma unroll
  for (int n = 0; n < 4; ++n)
    invc[n] = inv_n[gcol0 + wcol + n * 16 + lo] * C;
#pragma unroll
  for (int m = 0; m < 4; ++m)
#pragma unroll
    for (int r = 0; r < 4; ++r)
      invr[m][r] = inv_n[grow0 + wrow + m * 16 + hi * 4 + r];

  float rp[4][4] = {};
  float cp[4] = {};
#pragma unroll
  for (int m = 0; m < 4; ++m)
#pragma unroll
    for (int n = 0; n < 4; ++n)
#pragma unroll
      for (int r = 0; r < 4; ++r) {
        const int i = grow0 + wrow + m * 16 + hi * 4 + r;
        const int j = gcol0 + wcol + n * 16 + lo;
        float e2 = exp2f(acc[m][n][r] * invr[m][r] * invc[n]);
        if (j == i || j == i + N_ROWS) e2 = 0.0f;
        rp[m][r] += e2;
        cp[n] += e2;
      }

#pragma unroll
  for (int m = 0; m < 4; ++m)
#pragma unroll
    for (int r = 0; r < 4; ++r) {
      float v = rp[m][r];
      v += __shfl_xor(v, 1, 16);
      v += __shfl_xor(v, 2, 16);
      v += __shfl_xor(v, 4, 16);
      v += __shfl_xor(v, 8, 16);
      if (lo == 0)
        atomicAdd(&rowsum[grow0 + wrow + m * 16 + hi * 4 + r], v);
    }

  if (sym) {
#pragma unroll
    for (int n = 0; n < 4; ++n) {
      float v = cp[n];
      v += __shfl_xor(v, 16, 64);
      v += __shfl_xor(v, 32, 64);
      if (hi == 0)
        atomicAdd(&rowsum[gcol0 + wcol + n * 16 + lo], v);
    }
  }
}

// Single block: cumsum(rowsum) -> sum(log(neg) - logpos) + sum(js) -> out[0]
__global__ __launch_bounds__(256) void final_kernel(
    const float* __restrict__ rowsum, const float* __restrict__ logpos,
    const float* __restrict__ js, float* __restrict__ out) {
  __shared__ float scan[256];
  __shared__ double ds[4];
  __shared__ float fs[4];
  const int tid = threadIdx.x;
  float loc[16];
  float run = 0.f, jl = 0.f;
#pragma unroll
  for (int k = 0; k < 16; ++k) {
    loc[k] = rowsum[tid * 16 + k];
    run += loc[k];
    jl += js[tid * 16 + k];
  }
  scan[tid] = run;
  __syncthreads();
  for (int d = 1; d < 256; d <<= 1) {
    float add = (tid >= d) ? scan[tid - d] : 0.0f;
    __syncthreads();
    scan[tid] += add;
    __syncthreads();
  }
  float c = scan[tid] - run;  // exclusive prefix
  double acc = 0.0;
#pragma unroll
  for (int k = 0; k < 16; ++k) {
    c += loc[k];
    acc += (double)(logf(c) - logpos[tid * 16 + k]);
  }
#pragma unroll
  for (int m = 32; m >= 1; m >>= 1) {
    acc += __shfl_xor(acc, m, 64);
    jl  += __shfl_xor(jl, m, 64);
  }
  if ((tid & 63) == 0) { ds[tid >> 6] = acc; fs[tid >> 6] = jl; }
  __syncthreads();
  if (tid == 0) {
    const double nce = ds[0] + ds[1] + ds[2] + ds[3];
    const double jst = (double)(fs[0] + fs[1] + fs[2] + fs[3]);
    out[0] = (float)(nce + jst / (2.0 * N_ROWS));
  }
}

extern "C" void kernel_launch(void* const* d_in, const int* in_sizes, int n_in,
                              void* d_out, int out_size, void* d_ws, size_t ws_size,
                              hipStream_t stream) {
  const float* x = (const float*)d_in[0];
  const float* y = (const float*)d_in[1];
  float* out = (float*)d_out;

  char* ws = (char*)d_ws;
  unsigned char* Bb = (unsigned char*)ws;                  // [8192][1024] fp8 interleaved, 8 MB
  float* inv_n  = (float*)(ws + (size_t)8 * 1024 * 1024);  // 8192
  float* logpos = inv_n + 8192;                            // 4096
  float* rowsum = logpos + 4096;                           // 4096
  float* js     = rowsum + 4096;                           // 4096

  prep_kernel<<<N_ROWS / 4, 256, 0, stream>>>(x, y, Bb, inv_n, logpos, js, rowsum);
  gemm_fused<<<1552, 256, 0, stream>>>(Bb, inv_n, rowsum);
  final_kernel<<<1, 256, 0, stream>>>(rowsum, logpos, js, out);
}

// Round 13
// 72.688 us; speedup vs baseline: 4.9509x; 4.9509x over previous
//
#include <hip/hip_runtime.h>
#include <stdint.h>

#define N_ROWS 4096
#define D_DIM  1024
#define ROWB   1024   // bytes per row in fp8
#define T_TEMP 0.15f

#define AS1 __attribute__((address_space(1)))
#define AS3 __attribute__((address_space(3)))

typedef float f32x4  __attribute__((ext_vector_type(4)));
typedef int   i32x4v __attribute__((ext_vector_type(4)));

__device__ __forceinline__ float wsum(float v) {
#pragma unroll
  for (int m = 32; m >= 1; m >>= 1) v += __shfl_xor(v, m, 64);
  return v;
}
__device__ __forceinline__ float wmax(float v) {
#pragma unroll
  for (int m = 32; m >= 1; m >>= 1) v = fmaxf(v, __shfl_xor(v, m, 64));
  return v;
}

// One WAVE per row (no barriers): norms, x.y dot (-> log pos), softmax-JS
// per-row term -> js[row]. fp8-e4m3 casts stored INTERLEAVED into
// Bb = [x;y] (format verified end-to-end R10/R11, absmax 0). Zeroes rowsum.
__global__ __launch_bounds__(256) void prep_kernel(
    const float* __restrict__ x, const float* __restrict__ y,
    unsigned char* __restrict__ Bb, float* __restrict__ inv_n,
    float* __restrict__ logpos, float* __restrict__ js,
    float* __restrict__ rowsum) {
  if (threadIdx.x < 4) rowsum[blockIdx.x * 4 + threadIdx.x] = 0.0f;

  const int wid = threadIdx.x >> 6, lane = threadIdx.x & 63;
  const int row = blockIdx.x * 4 + wid;
  const float4* xp = (const float4*)(x + (size_t)row * D_DIM) + lane * 4;
  const float4* yp = (const float4*)(y + (size_t)row * D_DIM) + lane * 4;

  float xv[16], yv[16];
#pragma unroll
  for (int i = 0; i < 4; ++i) {
    float4 a = xp[i], b = yp[i];
    xv[i*4+0]=a.x; xv[i*4+1]=a.y; xv[i*4+2]=a.z; xv[i*4+3]=a.w;
    yv[i*4+0]=b.x; yv[i*4+1]=b.y; yv[i*4+2]=b.z; yv[i*4+3]=b.w;
  }

  float sx2=0.f, sy2=0.f, sxy=0.f, mx=-1e30f, my=-1e30f;
#pragma unroll
  for (int k = 0; k < 16; ++k) {
    sx2 = fmaf(xv[k], xv[k], sx2);
    sy2 = fmaf(yv[k], yv[k], sy2);
    sxy = fmaf(xv[k], yv[k], sxy);
    mx = fmaxf(mx, xv[k]); my = fmaxf(my, yv[k]);
  }
  sx2 = wsum(sx2); sy2 = wsum(sy2); sxy = wsum(sxy);
  mx = wmax(mx);  my = wmax(my);

  float ex[16], ey[16], sex=0.f, sey=0.f;
#pragma unroll
  for (int k = 0; k < 16; ++k) {
    ex[k] = __expf(xv[k] - mx); ey[k] = __expf(yv[k] - my);
    sex += ex[k]; sey += ey[k];
  }
  sex = wsum(sex); sey = wsum(sey);
  const float lsex = __logf(sex), lsey = __logf(sey);
  const float rsex = 1.f / sex,  rsey = 1.f / sey;

  float term = 0.f;
#pragma unroll
  for (int k = 0; k < 16; ++k) {
    float a = ex[k] * rsex, b = ey[k] * rsey;
    float lm = __logf(0.5f * (a + b));
    term += a * ((xv[k] - mx - lsex) - lm) + b * ((yv[k] - my - lsey) - lm);
  }
  term = wsum(term);

  if (lane == 0) {
    const float nx = sqrtf(sx2), ny = sqrtf(sy2);
    inv_n[row] = 1.f / nx;
    inv_n[N_ROWS + row] = 1.f / ny;
    logpos[row] = sxy / fmaxf(nx * ny, 1e-8f) / T_TEMP;  // ln(pos)
    js[row] = term;
  }

  int p[4], q[4];
#pragma unroll
  for (int w = 0; w < 4; ++w) {
    int v = 0;
    v = __builtin_amdgcn_cvt_pk_fp8_f32(xv[w*4+0], xv[w*4+1], v, false);
    v = __builtin_amdgcn_cvt_pk_fp8_f32(xv[w*4+2], xv[w*4+3], v, true);
    p[w] = v;
    int u = 0;
    u = __builtin_amdgcn_cvt_pk_fp8_f32(yv[w*4+0], yv[w*4+1], u, false);
    u = __builtin_amdgcn_cvt_pk_fp8_f32(yv[w*4+2], yv[w*4+3], u, true);
    q[w] = u;
  }
  // interleaved store: lane's 16 bytes = chunks (2l, 2l+1) of group l>>2,
  // kk = (l&3)>>1, h0 = (l&3 & 1)*2; dest = group*64 + h*16 + kk*8.
  const int ktp = lane >> 2;
  const int lq  = lane & 3;
  const int kkb = lq >> 1;
  const int h0  = (lq & 1) * 2;
  {
    char* ob = (char*)Bb + (size_t)row * ROWB + ktp * 64 + kkb * 8 + h0 * 16;
    *(int2*)(ob)      = make_int2(p[0], p[1]);
    *(int2*)(ob + 16) = make_int2(p[2], p[3]);
    char* oy = (char*)Bb + (size_t)(N_ROWS + row) * ROWB + ktp * 64 + kkb * 8 + h0 * 16;
    *(int2*)(oy)      = make_int2(q[0], q[1]);
    *(int2*)(oy + 16) = make_int2(q[2], q[3]);
  }
}

// ===== fp8 symmetric fused GEMM, 128x128, 4 waves, BK=64, DOUBLE-BUFFERED =====
// 2-phase pipeline (T3 minimum form): per K-tile {ds_read all frags from
// buf -> issue 4 GLL for tile kt+1 into buf^1 -> MFMA -> __syncthreads()}.
// One barrier/tile; the vmcnt(0) drained at the barrier covers loads issued
// a full compute-phase earlier (staging latency hidden under MFMA).
// LDS: per matrix 2 buffers of [128 rows][64B] (R11's measured-ZERO-conflict
// pattern: slot s of row r holds unit s ^ ((r>>1)&3); stage pre-swizzles the
// global source, reader XORs the same). One b128 = 2 K=32 MFMA operands
// (interleaved prep format, R10/R11-verified).
#define GLL(src, dst) __builtin_amdgcn_global_load_lds((const AS1 void*)(src), (AS3 void*)(dst), 16, 0, 0)

__global__ __launch_bounds__(256, 3) void gemm_fused(
    const unsigned char* __restrict__ Bb, const float* __restrict__ inv_n,
    float* __restrict__ rowsum) {
  __shared__ __align__(16) char As[2 * 8192];   // [buf][128][64]
  __shared__ __align__(16) char Bs[2 * 8192];
  const int tid = threadIdx.x;
  const int wid = tid >> 6, lane = tid & 63;
  const int lo = lane & 15, hi = lane >> 4;

  int bi, bj;
  bool sym = false;
  {
    const int idx = blockIdx.x;
    if (idx < 1024) {
      bi = idx >> 5; bj = 32 + (idx & 31);
    } else {
      const int t = idx - 1024;
      int b = (int)((65.0 - sqrt((double)(4225 - 8 * t))) * 0.5);
      while ((b + 1) * (65 - (b + 1)) / 2 <= t) ++b;
      while (b * (65 - b) / 2 > t) --b;
      bi = b;
      bj = b + (t - b * (65 - b) / 2);
      sym = (bi != bj);
    }
  }
  const int grow0 = bi * 128;
  const int gcol0 = bj * 128;
  const int wrow = (wid >> 1) * 64, wcol = (wid & 1) * 64;

  f32x4 acc[4][4] = {};

  // staging: thread t -> row sr = t>>2 (in each 64-row half), slot t&3;
  // source 16B unit pre-swizzled h = (t&3) ^ ((t>>3)&3)  (== (row>>1)&3).
  const int sr = tid >> 2;
  const int sh = (tid & 3) ^ ((tid >> 3) & 3);
  const char* gA = (const char*)Bb + (size_t)(grow0 + sr) * ROWB + sh * 16;
  const char* gB = (const char*)Bb + (size_t)(gcol0 + sr) * ROWB + sh * 16;

  // tile kt staging: 2 GLL per matrix (rows 0..63, 64..127), group = kt.
#define STG(kt_, b_) do { \
    GLL(gA + (size_t)(kt_) * 64,                      As + (b_) * 8192 + tid * 16); \
    GLL(gA + 64 * (size_t)ROWB + (size_t)(kt_) * 64,  As + (b_) * 8192 + 4096 + tid * 16); \
    GLL(gB + (size_t)(kt_) * 64,                      Bs + (b_) * 8192 + tid * 16); \
    GLL(gB + 64 * (size_t)ROWB + (size_t)(kt_) * 64,  Bs + (b_) * 8192 + 4096 + tid * 16); \
  } while (0)

  // fragment read: row = base + lo, slot = hi ^ xr (R11's zero-conflict pattern)
  const int xr = (lo >> 1) & 3;
  const int rslot = (hi ^ xr) * 16;

  union U { i32x4v v; long l[2]; };

  // prologue: stage tile 0 into buf 0 (syncthreads drains vmcnt)
  STG(0, 0);
  __syncthreads();

  for (int kt = 0; kt < 16; ++kt) {
    const int b = kt & 1;
    // 1) read all fragments of tile kt (before GLL issue: no LDS-alias stall)
    U a[4], bv[4];
#pragma unroll
    for (int m = 0; m < 4; ++m)
      a[m].v = *(const i32x4v*)(As + b * 8192 + (wrow + m * 16 + lo) * 64 + rslot);
#pragma unroll
    for (int n = 0; n < 4; ++n)
      bv[n].v = *(const i32x4v*)(Bs + b * 8192 + (wcol + n * 16 + lo) * 64 + rslot);
    // 2) issue staging for tile kt+1 into the other buffer
    if (kt < 15) STG(kt + 1, b ^ 1);
    // 3) MFMA (staging latency hides under this)
#pragma unroll
    for (int n = 0; n < 4; ++n)
#pragma unroll
      for (int m = 0; m < 4; ++m) {
        acc[m][n] = __builtin_amdgcn_mfma_f32_16x16x32_fp8_fp8(
            a[m].l[0], bv[n].l[0], acc[m][n], 0, 0, 0);
        acc[m][n] = __builtin_amdgcn_mfma_f32_16x16x32_fp8_fp8(
            a[m].l[1], bv[n].l[1], acc[m][n], 0, 0, 0);
      }
    // 4) one barrier per tile: drains vmcnt (staging visible) + read-before-
    //    overwrite safety for buf b (overwritten at kt+2's staging).
    __syncthreads();
  }

  // epilogue: scale -> exp2 -> mask diag -> row-reduce (+col-reduce if sym)
  const float C = 1.4426950408889634f / T_TEMP;   // log2(e)/T
  float invc[4], invr[4][4];
#pragma unroll
  for (int n = 0; n < 4; ++n)
    invc[n] = inv_n[gcol0 + wcol + n * 16 + lo] * C;
#pragma unroll
  for (int m = 0; m < 4; ++m)
#pragma unroll
    for (int r = 0; r < 4; ++r)
      invr[m][r] = inv_n[grow0 + wrow + m * 16 + hi * 4 + r];

  float rp[4][4] = {};
  float cp[4] = {};
#pragma unroll
  for (int m = 0; m < 4; ++m)
#pragma unroll
    for (int n = 0; n < 4; ++n)
#pragma unroll
      for (int r = 0; r < 4; ++r) {
        const int i = grow0 + wrow + m * 16 + hi * 4 + r;
        const int j = gcol0 + wcol + n * 16 + lo;
        float e2 = exp2f(acc[m][n][r] * invr[m][r] * invc[n]);
        if (j == i || j == i + N_ROWS) e2 = 0.0f;
        rp[m][r] += e2;
        cp[n] += e2;
      }

#pragma unroll
  for (int m = 0; m < 4; ++m)
#pragma unroll
    for (int r = 0; r < 4; ++r) {
      float v = rp[m][r];
      v += __shfl_xor(v, 1, 16);
      v += __shfl_xor(v, 2, 16);
      v += __shfl_xor(v, 4, 16);
      v += __shfl_xor(v, 8, 16);
      if (lo == 0)
        atomicAdd(&rowsum[grow0 + wrow + m * 16 + hi * 4 + r], v);
    }

  if (sym) {
#pragma unroll
    for (int n = 0; n < 4; ++n) {
      float v = cp[n];
      v += __shfl_xor(v, 16, 64);
      v += __shfl_xor(v, 32, 64);
      if (hi == 0)
        atomicAdd(&rowsum[gcol0 + wcol + n * 16 + lo], v);
    }
  }
#undef STG
}

// Single block: cumsum(rowsum) -> sum(log(neg) - logpos) + sum(js) -> out[0]
__global__ __launch_bounds__(256) void final_kernel(
    const float* __restrict__ rowsum, const float* __restrict__ logpos,
    const float* __restrict__ js, float* __restrict__ out) {
  __shared__ float scan[256];
  __shared__ double ds[4];
  __shared__ float fs[4];
  const int tid = threadIdx.x;
  float loc[16];
  float run = 0.f, jl = 0.f;
#pragma unroll
  for (int k = 0; k < 16; ++k) {
    loc[k] = rowsum[tid * 16 + k];
    run += loc[k];
    jl += js[tid * 16 + k];
  }
  scan[tid] = run;
  __syncthreads();
  for (int d = 1; d < 256; d <<= 1) {
    float add = (tid >= d) ? scan[tid - d] : 0.0f;
    __syncthreads();
    scan[tid] += add;
    __syncthreads();
  }
  float c = scan[tid] - run;  // exclusive prefix
  double acc = 0.0;
#pragma unroll
  for (int k = 0; k < 16; ++k) {
    c += loc[k];
    acc += (double)(logf(c) - logpos[tid * 16 + k]);
  }
#pragma unroll
  for (int m = 32; m >= 1; m >>= 1) {
    acc += __shfl_xor(acc, m, 64);
    jl  += __shfl_xor(jl, m, 64);
  }
  if ((tid & 63) == 0) { ds[tid >> 6] = acc; fs[tid >> 6] = jl; }
  __syncthreads();
  if (tid == 0) {
    const double nce = ds[0] + ds[1] + ds[2] + ds[3];
    const double jst = (double)(fs[0] + fs[1] + fs[2] + fs[3]);
    out[0] = (float)(nce + jst / (2.0 * N_ROWS));
  }
}

extern "C" void kernel_launch(void* const* d_in, const int* in_sizes, int n_in,
                              void* d_out, int out_size, void* d_ws, size_t ws_size,
                              hipStream_t stream) {
  const float* x = (const float*)d_in[0];
  const float* y = (const float*)d_in[1];
  float* out = (float*)d_out;

  char* ws = (char*)d_ws;
  unsigned char* Bb = (unsigned char*)ws;                  // [8192][1024] fp8 interleaved, 8 MB
  float* inv_n  = (float*)(ws + (size_t)8 * 1024 * 1024);  // 8192
  float* logpos = inv_n + 8192;                            // 4096
  float* rowsum = logpos + 4096;                           // 4096
  float* js     = rowsum + 4096;                           // 4096

  prep_kernel<<<N_ROWS / 4, 256, 0, stream>>>(x, y, Bb, inv_n, logpos, js, rowsum);
  gemm_fused<<<1552, 256, 0, stream>>>(Bb, inv_n, rowsum);
  final_kernel<<<1, 256, 0, stream>>>(rowsum, logpos, js, out);
}

// Round 14
// 67.062 us; speedup vs baseline: 5.3662x; 1.0839x over previous
//
#include <hip/hip_runtime.h>
#include <stdint.h>

#define N_ROWS 4096
#define D_DIM  1024
#define ROWB   1024   // bytes per row in fp8
#define T_TEMP 0.15f

#define AS1 __attribute__((address_space(1)))
#define AS3 __attribute__((address_space(3)))

typedef float f32x4  __attribute__((ext_vector_type(4)));
typedef int   i32x4v __attribute__((ext_vector_type(4)));

__device__ __forceinline__ float wsum(float v) {
#pragma unroll
  for (int m = 32; m >= 1; m >>= 1) v += __shfl_xor(v, m, 64);
  return v;
}
__device__ __forceinline__ float wmax(float v) {
#pragma unroll
  for (int m = 32; m >= 1; m >>= 1) v = fmaxf(v, __shfl_xor(v, m, 64));
  return v;
}

// One WAVE per row (no barriers): norms, x.y dot (-> log pos), softmax-JS
// per-row term -> js[row]. fp8-e4m3 casts stored INTERLEAVED into
// Bb = [x;y] (format verified end-to-end R10-R13, absmax 0). Zeroes rowsum.
__global__ __launch_bounds__(256) void prep_kernel(
    const float* __restrict__ x, const float* __restrict__ y,
    unsigned char* __restrict__ Bb, float* __restrict__ inv_n,
    float* __restrict__ logpos, float* __restrict__ js,
    float* __restrict__ rowsum) {
  if (threadIdx.x < 4) rowsum[blockIdx.x * 4 + threadIdx.x] = 0.0f;

  const int wid = threadIdx.x >> 6, lane = threadIdx.x & 63;
  const int row = blockIdx.x * 4 + wid;
  const float4* xp = (const float4*)(x + (size_t)row * D_DIM) + lane * 4;
  const float4* yp = (const float4*)(y + (size_t)row * D_DIM) + lane * 4;

  float xv[16], yv[16];
#pragma unroll
  for (int i = 0; i < 4; ++i) {
    float4 a = xp[i], b = yp[i];
    xv[i*4+0]=a.x; xv[i*4+1]=a.y; xv[i*4+2]=a.z; xv[i*4+3]=a.w;
    yv[i*4+0]=b.x; yv[i*4+1]=b.y; yv[i*4+2]=b.z; yv[i*4+3]=b.w;
  }

  float sx2=0.f, sy2=0.f, sxy=0.f, mx=-1e30f, my=-1e30f;
#pragma unroll
  for (int k = 0; k < 16; ++k) {
    sx2 = fmaf(xv[k], xv[k], sx2);
    sy2 = fmaf(yv[k], yv[k], sy2);
    sxy = fmaf(xv[k], yv[k], sxy);
    mx = fmaxf(mx, xv[k]); my = fmaxf(my, yv[k]);
  }
  sx2 = wsum(sx2); sy2 = wsum(sy2); sxy = wsum(sxy);
  mx = wmax(mx);  my = wmax(my);

  float ex[16], ey[16], sex=0.f, sey=0.f;
#pragma unroll
  for (int k = 0; k < 16; ++k) {
    ex[k] = __expf(xv[k] - mx); ey[k] = __expf(yv[k] - my);
    sex += ex[k]; sey += ey[k];
  }
  sex = wsum(sex); sey = wsum(sey);
  const float lsex = __logf(sex), lsey = __logf(sey);
  const float rsex = 1.f / sex,  rsey = 1.f / sey;

  float term = 0.f;
#pragma unroll
  for (int k = 0; k < 16; ++k) {
    float a = ex[k] * rsex, b = ey[k] * rsey;
    float lm = __logf(0.5f * (a + b));
    term += a * ((xv[k] - mx - lsex) - lm) + b * ((yv[k] - my - lsey) - lm);
  }
  term = wsum(term);

  if (lane == 0) {
    const float nx = sqrtf(sx2), ny = sqrtf(sy2);
    inv_n[row] = 1.f / nx;
    inv_n[N_ROWS + row] = 1.f / ny;
    logpos[row] = sxy / fmaxf(nx * ny, 1e-8f) / T_TEMP;  // ln(pos)
    js[row] = term;
  }

  int p[4], q[4];
#pragma unroll
  for (int w = 0; w < 4; ++w) {
    int v = 0;
    v = __builtin_amdgcn_cvt_pk_fp8_f32(xv[w*4+0], xv[w*4+1], v, false);
    v = __builtin_amdgcn_cvt_pk_fp8_f32(xv[w*4+2], xv[w*4+3], v, true);
    p[w] = v;
    int u = 0;
    u = __builtin_amdgcn_cvt_pk_fp8_f32(yv[w*4+0], yv[w*4+1], u, false);
    u = __builtin_amdgcn_cvt_pk_fp8_f32(yv[w*4+2], yv[w*4+3], u, true);
    q[w] = u;
  }
  // interleaved store: lane's 16 bytes = chunks (2l, 2l+1) of group l>>2,
  // kk = (l&3)>>1, h0 = (l&3 & 1)*2; dest = group*64 + h*16 + kk*8.
  const int ktp = lane >> 2;
  const int lq  = lane & 3;
  const int kkb = lq >> 1;
  const int h0  = (lq & 1) * 2;
  {
    char* ob = (char*)Bb + (size_t)row * ROWB + ktp * 64 + kkb * 8 + h0 * 16;
    *(int2*)(ob)      = make_int2(p[0], p[1]);
    *(int2*)(ob + 16) = make_int2(p[2], p[3]);
    char* oy = (char*)Bb + (size_t)(N_ROWS + row) * ROWB + ktp * 64 + kkb * 8 + h0 * 16;
    *(int2*)(oy)      = make_int2(q[0], q[1]);
    *(int2*)(oy + 16) = make_int2(q[2], q[3]);
  }
}

// ===== fp8 symmetric fused GEMM, 128x128, 4 waves, BK=64, raw 2-phase =====
// Per tile: {ds_read 8 frags from buf b | STG 4 GLL of kt+1 into b^1 |
// lgkmcnt(0)+SBAR | 32 MFMA | SBAR | vmcnt(0) | s_barrier}. sched_barrier(0)
// pins the order (rule: hipcc hoists reg-only MFMA past asm waits); the
// vmcnt(0) sits AFTER the MFMA block so the staging latency hides under it.
// Ledger: outstanding at drain = exactly the 4 GLLs of kt+1 (issued
// pre-MFMA); barrier publishes all waves' b^1 writes before tile kt+1 reads;
// buf b reads complete at lgkmcnt(0) and b is overwritten only at kt+1. LDS
// layout/swizzle byte-identical to R11 (measured 0 conflicts, absmax 0).
#define GLL(src, dst) __builtin_amdgcn_global_load_lds((const AS1 void*)(src), (AS3 void*)(dst), 16, 0, 0)
#define SBAR __builtin_amdgcn_sched_barrier(0)

__global__ __launch_bounds__(256, 3) void gemm_fused(
    const unsigned char* __restrict__ Bb, const float* __restrict__ inv_n,
    float* __restrict__ rowsum) {
  __shared__ __align__(16) char As[2 * 8192];   // [buf][128][64]
  __shared__ __align__(16) char Bs[2 * 8192];
  const int tid = threadIdx.x;
  const int wid = tid >> 6, lane = tid & 63;
  const int lo = lane & 15, hi = lane >> 4;

  int bi, bj;
  bool sym = false;
  {
    const int idx = blockIdx.x;
    if (idx < 1024) {
      bi = idx >> 5; bj = 32 + (idx & 31);
    } else {
      const int t = idx - 1024;
      int b = (int)((65.0 - sqrt((double)(4225 - 8 * t))) * 0.5);
      while ((b + 1) * (65 - (b + 1)) / 2 <= t) ++b;
      while (b * (65 - b) / 2 > t) --b;
      bi = b;
      bj = b + (t - b * (65 - b) / 2);
      sym = (bi != bj);
    }
  }
  const int grow0 = bi * 128;
  const int gcol0 = bj * 128;
  const int wrow = (wid >> 1) * 64, wcol = (wid & 1) * 64;

  f32x4 acc[4][4] = {};

  // staging: thread t -> row sr = t>>2 (per 64-row half), slot t&3;
  // source 16B unit pre-swizzled h = (t&3) ^ ((t>>3)&3) (== (row>>1)&3).
  const int sr = tid >> 2;
  const int sh = (tid & 3) ^ ((tid >> 3) & 3);
  const char* gA = (const char*)Bb + (size_t)(grow0 + sr) * ROWB + sh * 16;
  const char* gB = (const char*)Bb + (size_t)(gcol0 + sr) * ROWB + sh * 16;

#define STG(kt_, b_) do { \
    GLL(gA + (size_t)(kt_) * 64,                      As + (b_) * 8192 + tid * 16); \
    GLL(gA + 64 * (size_t)ROWB + (size_t)(kt_) * 64,  As + (b_) * 8192 + 4096 + tid * 16); \
    GLL(gB + (size_t)(kt_) * 64,                      Bs + (b_) * 8192 + tid * 16); \
    GLL(gB + 64 * (size_t)ROWB + (size_t)(kt_) * 64,  Bs + (b_) * 8192 + 4096 + tid * 16); \
  } while (0)

  // fragment read: row = base + lo, slot = hi ^ xr (zero-conflict pattern)
  const int xr = (lo >> 1) & 3;
  const int rslot = (hi ^ xr) * 16;

  union U { i32x4v v; long l[2]; };

#define RD_FRAGS(b_) do { _Pragma("unroll") \
    for (int m = 0; m < 4; ++m) \
      a[m].v = *(const i32x4v*)(As + (b_) * 8192 + (wrow + m * 16 + lo) * 64 + rslot); \
    _Pragma("unroll") \
    for (int n = 0; n < 4; ++n) \
      bv[n].v = *(const i32x4v*)(Bs + (b_) * 8192 + (wcol + n * 16 + lo) * 64 + rslot); \
  } while (0)

#define MFMA32 do { _Pragma("unroll") \
    for (int n = 0; n < 4; ++n) \
      _Pragma("unroll") \
      for (int m = 0; m < 4; ++m) { \
        acc[m][n] = __builtin_amdgcn_mfma_f32_16x16x32_fp8_fp8( \
            a[m].l[0], bv[n].l[0], acc[m][n], 0, 0, 0); \
        acc[m][n] = __builtin_amdgcn_mfma_f32_16x16x32_fp8_fp8( \
            a[m].l[1], bv[n].l[1], acc[m][n], 0, 0, 0); \
      } \
  } while (0)

  // prologue: stage tile 0 into buf 0, publish
  STG(0, 0);
  asm volatile("s_waitcnt vmcnt(0)" ::: "memory");
  __builtin_amdgcn_s_barrier();

  U a[4], bv[4];
#pragma unroll 1
  for (int kt = 0; kt < 15; ++kt) {
    const int b = kt & 1;
    RD_FRAGS(b);                 // 8 ds_read_b128 from buf b
    SBAR;
    STG(kt + 1, b ^ 1);          // issue 4 GLL for next tile
    asm volatile("s_waitcnt lgkmcnt(0)" ::: "memory");
    SBAR;                        // pin: no MFMA above this point
    __builtin_amdgcn_s_setprio(1);
    MFMA32;
    __builtin_amdgcn_s_setprio(0);
    SBAR;                        // pin: drain stays after MFMA
    asm volatile("s_waitcnt vmcnt(0)" ::: "memory");  // kt+1 landed (shadowed)
    __builtin_amdgcn_s_barrier();
  }
  // tail tile 15 (buf 1): no staging, no trailing barrier needed
  RD_FRAGS(1);
  asm volatile("s_waitcnt lgkmcnt(0)" ::: "memory");
  SBAR;
  MFMA32;

  // epilogue: scale -> exp2 -> mask diag -> row-reduce (+col-reduce if sym)
  const float C = 1.4426950408889634f / T_TEMP;   // log2(e)/T
  float invc[4], invr[4][4];
#pragma unroll
  for (int n = 0; n < 4; ++n)
    invc[n] = inv_n[gcol0 + wcol + n * 16 + lo] * C;
#pragma unroll
  for (int m = 0; m < 4; ++m)
#pragma unroll
    for (int r = 0; r < 4; ++r)
      invr[m][r] = inv_n[grow0 + wrow + m * 16 + hi * 4 + r];

  float rp[4][4] = {};
  float cp[4] = {};
#pragma unroll
  for (int m = 0; m < 4; ++m)
#pragma unroll
    for (int n = 0; n < 4; ++n)
#pragma unroll
      for (int r = 0; r < 4; ++r) {
        const int i = grow0 + wrow + m * 16 + hi * 4 + r;
        const int j = gcol0 + wcol + n * 16 + lo;
        float e2 = exp2f(acc[m][n][r] * invr[m][r] * invc[n]);
        if (j == i || j == i + N_ROWS) e2 = 0.0f;
        rp[m][r] += e2;
        cp[n] += e2;
      }

#pragma unroll
  for (int m = 0; m < 4; ++m)
#pragma unroll
    for (int r = 0; r < 4; ++r) {
      float v = rp[m][r];
      v += __shfl_xor(v, 1, 16);
      v += __shfl_xor(v, 2, 16);
      v += __shfl_xor(v, 4, 16);
      v += __shfl_xor(v, 8, 16);
      if (lo == 0)
        atomicAdd(&rowsum[grow0 + wrow + m * 16 + hi * 4 + r], v);
    }

  if (sym) {
#pragma unroll
    for (int n = 0; n < 4; ++n) {
      float v = cp[n];
      v += __shfl_xor(v, 16, 64);
      v += __shfl_xor(v, 32, 64);
      if (hi == 0)
        atomicAdd(&rowsum[gcol0 + wcol + n * 16 + lo], v);
    }
  }
#undef STG
#undef RD_FRAGS
#undef MFMA32
}

// Single block: cumsum(rowsum) -> sum(log(neg) - logpos) + sum(js) -> out[0]
__global__ __launch_bounds__(256) void final_kernel(
    const float* __restrict__ rowsum, const float* __restrict__ logpos,
    const float* __restrict__ js, float* __restrict__ out) {
  __shared__ float scan[256];
  __shared__ double ds[4];
  __shared__ float fs[4];
  const int tid = threadIdx.x;
  float loc[16];
  float run = 0.f, jl = 0.f;
#pragma unroll
  for (int k = 0; k < 16; ++k) {
    loc[k] = rowsum[tid * 16 + k];
    run += loc[k];
    jl += js[tid * 16 + k];
  }
  scan[tid] = run;
  __syncthreads();
  for (int d = 1; d < 256; d <<= 1) {
    float add = (tid >= d) ? scan[tid - d] : 0.0f;
    __syncthreads();
    scan[tid] += add;
    __syncthreads();
  }
  float c = scan[tid] - run;  // exclusive prefix
  double acc = 0.0;
#pragma unroll
  for (int k = 0; k < 16; ++k) {
    c += loc[k];
    acc += (double)(logf(c) - logpos[tid * 16 + k]);
  }
#pragma unroll
  for (int m = 32; m >= 1; m >>= 1) {
    acc += __shfl_xor(acc, m, 64);
    jl  += __shfl_xor(jl, m, 64);
  }
  if ((tid & 63) == 0) { ds[tid >> 6] = acc; fs[tid >> 6] = jl; }
  __syncthreads();
  if (tid == 0) {
    const double nce = ds[0] + ds[1] + ds[2] + ds[3];
    const double jst = (double)(fs[0] + fs[1] + fs[2] + fs[3]);
    out[0] = (float)(nce + jst / (2.0 * N_ROWS));
  }
}

extern "C" void kernel_launch(void* const* d_in, const int* in_sizes, int n_in,
                              void* d_out, int out_size, void* d_ws, size_t ws_size,
                              hipStream_t stream) {
  const float* x = (const float*)d_in[0];
  const float* y = (const float*)d_in[1];
  float* out = (float*)d_out;

  char* ws = (char*)d_ws;
  unsigned char* Bb = (unsigned char*)ws;                  // [8192][1024] fp8 interleaved, 8 MB
  float* inv_n  = (float*)(ws + (size_t)8 * 1024 * 1024);  // 8192
  float* logpos = inv_n + 8192;                            // 4096
  float* rowsum = logpos + 4096;                           // 4096
  float* js     = rowsum + 4096;                           // 4096

  prep_kernel<<<N_ROWS / 4, 256, 0, stream>>>(x, y, Bb, inv_n, logpos, js, rowsum);
  gemm_fused<<<1552, 256, 0, stream>>>(Bb, inv_n, rowsum);
  final_kernel<<<1, 256, 0, stream>>>(rowsum, logpos, js, out);
}

// Round 15
// 65.755 us; speedup vs baseline: 5.4729x; 1.0199x over previous
//
#include <hip/hip_runtime.h>
#include <stdint.h>

#define N_ROWS 4096
#define D_DIM  1024
#define ROWB   1024   // bytes per row in i8
#define T_TEMP 0.15f

#define AS1 __attribute__((address_space(1)))
#define AS3 __attribute__((address_space(3)))

typedef int i32x4v __attribute__((ext_vector_type(4)));

__device__ __forceinline__ float wsum(float v) {
#pragma unroll
  for (int m = 32; m >= 1; m >>= 1) v += __shfl_xor(v, m, 64);
  return v;
}
__device__ __forceinline__ float wmax(float v) {
#pragma unroll
  for (int m = 32; m >= 1; m >>= 1) v = fmaxf(v, __shfl_xor(v, m, 64));
  return v;
}

// One WAVE per row (no barriers): norms, x.y dot (-> log pos), softmax-JS
// per-row term -> js[row]. Per-row symmetric i8 quantization (scale
// cancels in cosine): q = rint(x * 127/rowmax|x|), natural row-major
// layout in Bb = [x;y]; inv_n = 1/|q|. Zeroes rowsum.
__global__ __launch_bounds__(256) void prep_kernel(
    const float* __restrict__ x, const float* __restrict__ y,
    unsigned char* __restrict__ Bb, float* __restrict__ inv_n,
    float* __restrict__ logpos, float* __restrict__ js,
    float* __restrict__ rowsum) {
  if (threadIdx.x < 4) rowsum[blockIdx.x * 4 + threadIdx.x] = 0.0f;

  const int wid = threadIdx.x >> 6, lane = threadIdx.x & 63;
  const int row = blockIdx.x * 4 + wid;
  const float4* xp = (const float4*)(x + (size_t)row * D_DIM) + lane * 4;
  const float4* yp = (const float4*)(y + (size_t)row * D_DIM) + lane * 4;

  float xv[16], yv[16];
#pragma unroll
  for (int i = 0; i < 4; ++i) {
    float4 a = xp[i], b = yp[i];
    xv[i*4+0]=a.x; xv[i*4+1]=a.y; xv[i*4+2]=a.z; xv[i*4+3]=a.w;
    yv[i*4+0]=b.x; yv[i*4+1]=b.y; yv[i*4+2]=b.z; yv[i*4+3]=b.w;
  }

  float sx2=0.f, sy2=0.f, sxy=0.f, mx=-1e30f, my=-1e30f, ax=0.f, ay=0.f;
#pragma unroll
  for (int k = 0; k < 16; ++k) {
    sx2 = fmaf(xv[k], xv[k], sx2);
    sy2 = fmaf(yv[k], yv[k], sy2);
    sxy = fmaf(xv[k], yv[k], sxy);
    mx = fmaxf(mx, xv[k]); my = fmaxf(my, yv[k]);
    ax = fmaxf(ax, fabsf(xv[k])); ay = fmaxf(ay, fabsf(yv[k]));
  }
  sx2 = wsum(sx2); sy2 = wsum(sy2); sxy = wsum(sxy);
  mx = wmax(mx);  my = wmax(my);
  ax = wmax(ax);  ay = wmax(ay);

  float ex[16], ey[16], sex=0.f, sey=0.f;
#pragma unroll
  for (int k = 0; k < 16; ++k) {
    ex[k] = __expf(xv[k] - mx); ey[k] = __expf(yv[k] - my);
    sex += ex[k]; sey += ey[k];
  }
  sex = wsum(sex); sey = wsum(sey);
  const float lsex = __logf(sex), lsey = __logf(sey);
  const float rsex = 1.f / sex,  rsey = 1.f / sey;

  float term = 0.f;
#pragma unroll
  for (int k = 0; k < 16; ++k) {
    float a = ex[k] * rsex, b = ey[k] * rsey;
    float lm = __logf(0.5f * (a + b));
    term += a * ((xv[k] - mx - lsex) - lm) + b * ((yv[k] - my - lsey) - lm);
  }
  term = wsum(term);

  // quantize: q = rint(x * 127/rowmax); accumulate |q|^2
  const float sxq = 127.0f / ax, syq = 127.0f / ay;
  int qx[16], qy[16];
  float q2x = 0.f, q2y = 0.f;
#pragma unroll
  for (int k = 0; k < 16; ++k) {
    qx[k] = (int)rintf(xv[k] * sxq);
    qy[k] = (int)rintf(yv[k] * syq);
    q2x += (float)(qx[k] * qx[k]);
    q2y += (float)(qy[k] * qy[k]);
  }
  q2x = wsum(q2x); q2y = wsum(q2y);

  if (lane == 0) {
    const float nx = sqrtf(sx2), ny = sqrtf(sy2);
    inv_n[row] = rsqrtf(q2x);            // 1/|q_x|
    inv_n[N_ROWS + row] = rsqrtf(q2y);   // 1/|q_y|
    logpos[row] = sxy / fmaxf(nx * ny, 1e-8f) / T_TEMP;  // ln(pos), exact fp32
    js[row] = term;
  }

  int p[4], q[4];
#pragma unroll
  for (int w = 0; w < 4; ++w) {
    p[w] = (qx[4*w] & 255) | ((qx[4*w+1] & 255) << 8) |
           ((qx[4*w+2] & 255) << 16) | ((qx[4*w+3] & 255) << 24);
    q[w] = (qy[4*w] & 255) | ((qy[4*w+1] & 255) << 8) |
           ((qy[4*w+2] & 255) << 16) | ((qy[4*w+3] & 255) << 24);
  }
  *(int4*)(Bb + (size_t)row * ROWB + lane * 16) = make_int4(p[0], p[1], p[2], p[3]);
  *(int4*)(Bb + (size_t)(N_ROWS + row) * ROWB + lane * 16) = make_int4(q[0], q[1], q[2], q[3]);
}

// ===== i8 symmetric fused GEMM, 128x128, 4 waves, BK=64, raw 2-phase =====
// Schedule/addressing byte-identical to R14 (measured: conflicts 0, best
// gemm). One b128 = one full K=64 i8 operand (mfma_i32_16x16x64_i8, 1.9x
// fp8 rate; 16 MFMA per tile instead of 32). Slot-swizzle delivers natural
// k-unit hi to every lane for BOTH A and B (k-permutation-safe).
#define GLL(src, dst) __builtin_amdgcn_global_load_lds((const AS1 void*)(src), (AS3 void*)(dst), 16, 0, 0)
#define SBAR __builtin_amdgcn_sched_barrier(0)

__global__ __launch_bounds__(256, 3) void gemm_fused(
    const unsigned char* __restrict__ Bb, const float* __restrict__ inv_n,
    float* __restrict__ rowsum) {
  __shared__ __align__(16) char As[2 * 8192];   // [buf][128][64]
  __shared__ __align__(16) char Bs[2 * 8192];
  const int tid = threadIdx.x;
  const int wid = tid >> 6, lane = tid & 63;
  const int lo = lane & 15, hi = lane >> 4;

  int bi, bj;
  bool sym = false;
  {
    const int idx = blockIdx.x;
    if (idx < 1024) {
      bi = idx >> 5; bj = 32 + (idx & 31);
    } else {
      const int t = idx - 1024;
      int b = (int)((65.0 - sqrt((double)(4225 - 8 * t))) * 0.5);
      while ((b + 1) * (65 - (b + 1)) / 2 <= t) ++b;
      while (b * (65 - b) / 2 > t) --b;
      bi = b;
      bj = b + (t - b * (65 - b) / 2);
      sym = (bi != bj);
    }
  }
  const int grow0 = bi * 128;
  const int gcol0 = bj * 128;
  const int wrow = (wid >> 1) * 64, wcol = (wid & 1) * 64;

  i32x4v acc[4][4] = {};

  // staging: thread t -> row sr = t>>2 (per 64-row half), slot t&3;
  // source 16B unit pre-swizzled h = (t&3) ^ ((t>>3)&3) (== (row>>1)&3).
  const int sr = tid >> 2;
  const int sh = (tid & 3) ^ ((tid >> 3) & 3);
  const char* gA = (const char*)Bb + (size_t)(grow0 + sr) * ROWB + sh * 16;
  const char* gB = (const char*)Bb + (size_t)(gcol0 + sr) * ROWB + sh * 16;

#define STG(kt_, b_) do { \
    GLL(gA + (size_t)(kt_) * 64,                      As + (b_) * 8192 + tid * 16); \
    GLL(gA + 64 * (size_t)ROWB + (size_t)(kt_) * 64,  As + (b_) * 8192 + 4096 + tid * 16); \
    GLL(gB + (size_t)(kt_) * 64,                      Bs + (b_) * 8192 + tid * 16); \
    GLL(gB + 64 * (size_t)ROWB + (size_t)(kt_) * 64,  Bs + (b_) * 8192 + 4096 + tid * 16); \
  } while (0)

  // fragment read: row = base + lo, slot = hi ^ xr (zero-conflict pattern);
  // delivered bytes = natural k-unit hi (k = hi*16..hi*16+15) for all rows.
  const int xr = (lo >> 1) & 3;
  const int rslot = (hi ^ xr) * 16;

  i32x4v a[4], bv[4];

#define RD_FRAGS(b_) do { _Pragma("unroll") \
    for (int m = 0; m < 4; ++m) \
      a[m] = *(const i32x4v*)(As + (b_) * 8192 + (wrow + m * 16 + lo) * 64 + rslot); \
    _Pragma("unroll") \
    for (int n = 0; n < 4; ++n) \
      bv[n] = *(const i32x4v*)(Bs + (b_) * 8192 + (wcol + n * 16 + lo) * 64 + rslot); \
  } while (0)

#define MFMA16 do { _Pragma("unroll") \
    for (int n = 0; n < 4; ++n) \
      _Pragma("unroll") \
      for (int m = 0; m < 4; ++m) \
        acc[m][n] = __builtin_amdgcn_mfma_i32_16x16x64_i8( \
            a[m], bv[n], acc[m][n], 0, 0, 0); \
  } while (0)

  // prologue: stage tile 0 into buf 0, publish
  STG(0, 0);
  asm volatile("s_waitcnt vmcnt(0)" ::: "memory");
  __builtin_amdgcn_s_barrier();

#pragma unroll 1
  for (int kt = 0; kt < 15; ++kt) {
    const int b = kt & 1;
    RD_FRAGS(b);                 // 8 ds_read_b128 from buf b
    SBAR;
    STG(kt + 1, b ^ 1);          // issue 4 GLL for next tile
    asm volatile("s_waitcnt lgkmcnt(0)" ::: "memory");
    SBAR;                        // pin: no MFMA above this point
    __builtin_amdgcn_s_setprio(1);
    MFMA16;
    __builtin_amdgcn_s_setprio(0);
    SBAR;                        // pin: drain stays after MFMA
    asm volatile("s_waitcnt vmcnt(0)" ::: "memory");  // kt+1 landed (shadowed)
    __builtin_amdgcn_s_barrier();
  }
  // tail tile 15 (buf 1): no staging, no trailing barrier needed
  RD_FRAGS(1);
  asm volatile("s_waitcnt lgkmcnt(0)" ::: "memory");
  SBAR;
  MFMA16;

  // epilogue: scale -> exp2 -> mask diag -> row-reduce (+col-reduce if sym)
  const float C = 1.4426950408889634f / T_TEMP;   // log2(e)/T
  float invc[4], invr[4][4];
#pragma unroll
  for (int n = 0; n < 4; ++n)
    invc[n] = inv_n[gcol0 + wcol + n * 16 + lo] * C;
#pragma unroll
  for (int m = 0; m < 4; ++m)
#pragma unroll
    for (int r = 0; r < 4; ++r)
      invr[m][r] = inv_n[grow0 + wrow + m * 16 + hi * 4 + r];

  float rp[4][4] = {};
  float cp[4] = {};
#pragma unroll
  for (int m = 0; m < 4; ++m)
#pragma unroll
    for (int n = 0; n < 4; ++n)
#pragma unroll
      for (int r = 0; r < 4; ++r) {
        const int i = grow0 + wrow + m * 16 + hi * 4 + r;
        const int j = gcol0 + wcol + n * 16 + lo;
        float e2 = exp2f((float)acc[m][n][r] * invr[m][r] * invc[n]);
        if (j == i || j == i + N_ROWS) e2 = 0.0f;
        rp[m][r] += e2;
        cp[n] += e2;
      }

#pragma unroll
  for (int m = 0; m < 4; ++m)
#pragma unroll
    for (int r = 0; r < 4; ++r) {
      float v = rp[m][r];
      v += __shfl_xor(v, 1, 16);
      v += __shfl_xor(v, 2, 16);
      v += __shfl_xor(v, 4, 16);
      v += __shfl_xor(v, 8, 16);
      if (lo == 0)
        atomicAdd(&rowsum[grow0 + wrow + m * 16 + hi * 4 + r], v);
    }

  if (sym) {
#pragma unroll
    for (int n = 0; n < 4; ++n) {
      float v = cp[n];
      v += __shfl_xor(v, 16, 64);
      v += __shfl_xor(v, 32, 64);
      if (hi == 0)
        atomicAdd(&rowsum[gcol0 + wcol + n * 16 + lo], v);
    }
  }
#undef STG
#undef RD_FRAGS
#undef MFMA16
}

// Single block: cumsum(rowsum) -> sum(log(neg) - logpos) + sum(js) -> out[0]
__global__ __launch_bounds__(256) void final_kernel(
    const float* __restrict__ rowsum, const float* __restrict__ logpos,
    const float* __restrict__ js, float* __restrict__ out) {
  __shared__ float scan[256];
  __shared__ double ds[4];
  __shared__ float fs[4];
  const int tid = threadIdx.x;
  float loc[16];
  float run = 0.f, jl = 0.f;
#pragma unroll
  for (int k = 0; k < 16; ++k) {
    loc[k] = rowsum[tid * 16 + k];
    run += loc[k];
    jl += js[tid * 16 + k];
  }
  scan[tid] = run;
  __syncthreads();
  for (int d = 1; d < 256; d <<= 1) {
    float add = (tid >= d) ? scan[tid - d] : 0.0f;
    __syncthreads();
    scan[tid] += add;
    __syncthreads();
  }
  float c = scan[tid] - run;  // exclusive prefix
  double acc = 0.0;
#pragma unroll
  for (int k = 0; k < 16; ++k) {
    c += loc[k];
    acc += (double)(logf(c) - logpos[tid * 16 + k]);
  }
#pragma unroll
  for (int m = 32; m >= 1; m >>= 1) {
    acc += __shfl_xor(acc, m, 64);
    jl  += __shfl_xor(jl, m, 64);
  }
  if ((tid & 63) == 0) { ds[tid >> 6] = acc; fs[tid >> 6] = jl; }
  __syncthreads();
  if (tid == 0) {
    const double nce = ds[0] + ds[1] + ds[2] + ds[3];
    const double jst = (double)(fs[0] + fs[1] + fs[2] + fs[3]);
    out[0] = (float)(nce + jst / (2.0 * N_ROWS));
  }
}

extern "C" void kernel_launch(void* const* d_in, const int* in_sizes, int n_in,
                              void* d_out, int out_size, void* d_ws, size_t ws_size,
                              hipStream_t stream) {
  const float* x = (const float*)d_in[0];
  const float* y = (const float*)d_in[1];
  float* out = (float*)d_out;

  char* ws = (char*)d_ws;
  unsigned char* Bb = (unsigned char*)ws;                  // [8192][1024] i8, 8 MB
  float* inv_n  = (float*)(ws + (size_t)8 * 1024 * 1024);  // 8192
  float* logpos = inv_n + 8192;                            // 4096
  float* rowsum = logpos + 4096;                           // 4096
  float* js     = rowsum + 4096;                           // 4096

  prep_kernel<<<N_ROWS / 4, 256, 0, stream>>>(x, y, Bb, inv_n, logpos, js, rowsum);
  gemm_fused<<<1552, 256, 0, stream>>>(Bb, inv_n, rowsum);
  final_kernel<<<1, 256, 0, stream>>>(rowsum, logpos, js, out);
}